// Round 1
// baseline (2761.488 us; speedup 1.0000x reference)
//
#include <hip/hip_runtime.h>
#include <hip/hip_bf16.h>
#include <cstdio>
#include <cstdint>

// Problem dims (fixed)
#define MDIM  4096   // batch
#define HDIM  2048   // hidden
#define SHDIM 4096   // 2H
#define KGATE 32768  // 8 * 2H
#define NDIM  2048   // output cols per gate

typedef __attribute__((ext_vector_type(8))) short short8;
typedef __attribute__((ext_vector_type(4))) float f32x4;
typedef unsigned short u16;

__device__ __forceinline__ u16 f2b(float f) {
  __hip_bfloat16 h = __float2bfloat16(f);
  return __builtin_bit_cast(u16, h);
}

// async global->LDS DMA, 16B per lane. LDS base must be wave-uniform;
// HW writes lane i's 16B at lbase + i*16.
__device__ __forceinline__ void gld_lds16(const u16* g, u16* l) {
  __builtin_amdgcn_global_load_lds((const __attribute__((address_space(1))) void*)g,
                                   (__attribute__((address_space(3))) void*)l,
                                   16, 0, 0);
}

// ---------------- ws layout (bytes) ----------------
static const size_t SZ_WT    = (size_t)NDIM * KGATE * 2;   // 134217728 (one gate W, bf16, [N,K])
static const size_t OFF_W1T  = 0;
static const size_t OFF_W2T  = OFF_W1T + SZ_WT;            // 134217728
static const size_t OFF_WMT  = OFF_W2T + SZ_WT;            // 268435456
static const size_t SZ_WMT   = (size_t)NDIM * SHDIM * 2;   // 16777216
static const size_t OFF_SBF  = OFF_WMT + SZ_WMT;           // 285212672
static const size_t SZ_SBF   = (size_t)MDIM * SHDIM * 2;   // 33554432
static const size_t OFF_Z    = OFF_SBF + SZ_SBF;           // 318767104
static const size_t SZ_Z     = (size_t)MDIM * KGATE * 2;   // 268435456
static const size_t FULL_NEED = OFF_Z + SZ_Z;              // 587202560 (560 MiB)

// ---------------- prep kernels ----------------

// src fp32 [R][C] row-major -> dst bf16 [C][R] row-major (k-major for GEMM B).
__global__ __launch_bounds__(256) void transpose_cvt(const float* __restrict__ src,
                                                     u16* __restrict__ dst,
                                                     int R, int C) {
  __shared__ u16 t[32][33];
  const int tx = threadIdx.x & 31, ty = threadIdx.x >> 5;  // ty 0..7
  const int r0 = blockIdx.y << 5, c0 = blockIdx.x << 5;
  #pragma unroll
  for (int i = ty; i < 32; i += 8)
    t[i][tx] = f2b(src[(size_t)(r0 + i) * C + (c0 + tx)]);
  __syncthreads();
  #pragma unroll
  for (int i = ty; i < 32; i += 8)
    dst[(size_t)(c0 + i) * R + (r0 + tx)] = t[tx][i];
}

// Build s_bf16 [M][4096] = bf16(concat(h0,h1)) and Z [M][32768], Z[l][i*4096+j]=bf16(x[l,i]*s[l,j])
__global__ __launch_bounds__(256) void build_sZ(const float* __restrict__ x0, const float* __restrict__ x1,
                                                const float* __restrict__ h0, const float* __restrict__ h1,
                                                u16* __restrict__ sbf, u16* __restrict__ Z) {
  const int l = blockIdx.x;
  float xv[8];
  #pragma unroll
  for (int i = 0; i < 4; ++i) { xv[i] = x0[l * 4 + i]; xv[4 + i] = x1[l * 4 + i]; }
  const float4* h0v = (const float4*)(h0 + (size_t)l * HDIM);
  const float4* h1v = (const float4*)(h1 + (size_t)l * HDIM);
  u16* srow = sbf + (size_t)l * SHDIM;
  u16* zrow = Z + (size_t)l * KGATE;
  for (int jj = threadIdx.x; jj < SHDIM / 4; jj += 256) {
    float4 sv = (jj < HDIM / 4) ? h0v[jj] : h1v[jj - HDIM / 4];
    ushort4 sb = make_ushort4(f2b(sv.x), f2b(sv.y), f2b(sv.z), f2b(sv.w));
    ((ushort4*)srow)[jj] = sb;
    #pragma unroll
    for (int i = 0; i < 8; ++i) {
      float xs = xv[i];
      ushort4 zb = make_ushort4(f2b(sv.x * xs), f2b(sv.y * xs), f2b(sv.z * xs), f2b(sv.w * xs));
      ((ushort4*)(zrow + (size_t)i * SHDIM))[jj] = zb;
    }
  }
}

// ---------------- fused epilogues ----------------
// EPI 0: merge GEMM result -> slot1
// EPI 1: g2: u = sigmoid(v+b2); slot1 = (1-u)*slot1; slot0 = u
// EPI 2: g1: st = tanh(v+b1); o = slot0*st + slot1; slot0 = slot1 = o
template <int EPI>
__device__ __forceinline__ void epi_store(float v, size_t idx, float bcol,
                                          float* slot0, float* slot1) {
  if constexpr (EPI == 0) {
    slot1[idx] = v;
  } else if constexpr (EPI == 1) {
    float u = 1.f / (1.f + __expf(-(v + bcol)));
    float m = slot1[idx];
    slot1[idx] = (1.f - u) * m;
    slot0[idx] = u;
  } else {
    float st = tanhf(v + bcol);
    float o = fmaf(slot0[idx], st, slot1[idx]);
    slot0[idx] = o;
    slot1[idx] = o;
  }
}

// ---------------- main MFMA GEMM (m97 structure) ----------------
// C[M,N] = A[M,K](bf16,k-major) * Bt[N,K](bf16,k-major)^T ; 128x128 block, BK=32,
// 4 waves of 64x64, v_mfma_f32_16x16x32_bf16, global_load_lds staging.
template <int EPI>
__global__ __launch_bounds__(256)
void gemm_epi(const u16* __restrict__ A, const u16* __restrict__ Bt, int K,
              const float* __restrict__ bias,
              float* __restrict__ slot0, float* __restrict__ slot1) {
  __shared__ __attribute__((aligned(16))) u16 Atile[128 * 32];
  __shared__ __attribute__((aligned(16))) u16 Btile[128 * 32];

  const int tid  = threadIdx.x;
  const int lane = tid & 63;
  const int wave = tid >> 6;
  const int wM = wave & 1;   // 2x2 wave grid
  const int wN = wave >> 1;
  const int mq = lane >> 4;  // 0..3 (k-group / row-group)
  const int mr = lane & 15;
  const int l4  = lane >> 2;        // row within 16-row DMA chunk
  const int k16 = (lane & 3) * 8;   // k element offset (16B granules)

  const size_t Abase = (size_t)blockIdx.x * 128 * K;
  const size_t Bbase = (size_t)blockIdx.y * 128 * K;

  f32x4 acc[4][4];
  const f32x4 zero = {0.f, 0.f, 0.f, 0.f};
  #pragma unroll
  for (int r = 0; r < 4; ++r)
    #pragma unroll
    for (int c = 0; c < 4; ++c) acc[r][c] = zero;

  const int nkt = K >> 5;
  for (int kt = 0; kt < nkt; ++kt) {
    const int kpos = (kt << 5) + k16;
    #pragma unroll
    for (int q = 0; q < 2; ++q) {
      const int chunk = wave * 2 + q;          // wave-uniform
      const int row = chunk * 16 + l4;
      gld_lds16(A + Abase + (size_t)row * K + kpos, Atile + chunk * 512);
      gld_lds16(Bt + Bbase + (size_t)row * K + kpos, Btile + chunk * 512);
    }
    __syncthreads();  // drains vmcnt(0) -> DMA visible
    short8 af[4], bfr[4];
    #pragma unroll
    for (int r = 0; r < 4; ++r)
      af[r] = *(const short8*)(Atile + (wM * 64 + r * 16 + mr) * 32 + mq * 8);
    #pragma unroll
    for (int c = 0; c < 4; ++c)
      bfr[c] = *(const short8*)(Btile + (wN * 64 + c * 16 + mr) * 32 + mq * 8);
    #pragma unroll
    for (int r = 0; r < 4; ++r)
      #pragma unroll
      for (int c = 0; c < 4; ++c)
        acc[r][c] = __builtin_amdgcn_mfma_f32_16x16x32_bf16(af[r], bfr[c], acc[r][c], 0, 0, 0);
    __syncthreads();  // protect tiles before next DMA
  }

  const int row0 = blockIdx.x * 128 + wM * 64;
  const int col0 = blockIdx.y * 128 + wN * 64;
  #pragma unroll
  for (int r = 0; r < 4; ++r) {
    #pragma unroll
    for (int c = 0; c < 4; ++c) {
      const int col = col0 + c * 16 + mr;
      float bcol = 0.f;
      if constexpr (EPI != 0) bcol = bias[col];
      #pragma unroll
      for (int e = 0; e < 4; ++e) {
        const int row = row0 + r * 16 + mq * 4 + e;  // C/D: col=lane&15, row=(lane>>4)*4+e
        epi_store<EPI>(acc[r][c][e], (size_t)row * NDIM + col, bcol, slot0, slot1);
      }
    }
  }
}

// ---------------- correct-but-slow fp32 fallback (if ws too small) ----------------
// 64x64 output tile, 16x16 threads x 4x4 each, LDS-tiled, z computed on the fly.
template <int EPI>
__global__ __launch_bounds__(256)
void slow_gemm(const float* __restrict__ x0, const float* __restrict__ x1,
               const float* __restrict__ h0, const float* __restrict__ h1,
               const float* __restrict__ W, int KK, const float* __restrict__ bias,
               float* __restrict__ slot0, float* __restrict__ slot1) {
  __shared__ float As[64][16];
  __shared__ float Bs[16][65];
  const int tx = threadIdx.x & 15, ty = threadIdx.x >> 4;
  const int bM = blockIdx.x, bN = blockIdx.y;
  float acc[4][4] = {};
  for (int k0 = 0; k0 < KK; k0 += 16) {
    for (int t = threadIdx.x; t < 64 * 16; t += 256) {
      int r = t >> 4, kk = t & 15;
      int gk = k0 + kk;
      int row = bM * 64 + r;
      int j = (EPI == 0) ? gk : (gk & (SHDIM - 1));
      float sv = (j < HDIM) ? h0[(size_t)row * HDIM + j] : h1[(size_t)row * HDIM + j - HDIM];
      if (EPI != 0) {
        int i = gk >> 12;
        float xvv = (i < 4) ? x0[row * 4 + i] : x1[row * 4 + i - 4];
        sv *= xvv;
      }
      As[r][kk] = sv;
    }
    for (int t = threadIdx.x; t < 16 * 64; t += 256) {
      int kk = t >> 6, n = t & 63;
      Bs[kk][n] = W[(size_t)(k0 + kk) * NDIM + bN * 64 + n];
    }
    __syncthreads();
    #pragma unroll
    for (int kk = 0; kk < 16; ++kk)
      #pragma unroll
      for (int a = 0; a < 4; ++a)
        #pragma unroll
        for (int b = 0; b < 4; ++b)
          acc[a][b] = fmaf(As[ty * 4 + a][kk], Bs[kk][tx * 4 + b], acc[a][b]);
    __syncthreads();
  }
  #pragma unroll
  for (int a = 0; a < 4; ++a)
    #pragma unroll
    for (int b = 0; b < 4; ++b) {
      int row = bM * 64 + ty * 4 + a, col = bN * 64 + tx * 4 + b;
      float bcol = (EPI != 0) ? bias[col] : 0.f;
      epi_store<EPI>(acc[a][b], (size_t)row * NDIM + col, bcol, slot0, slot1);
    }
}

// ---------------- host ----------------
extern "C" void kernel_launch(void* const* d_in, const int* in_sizes, int n_in,
                              void* d_out, int out_size, void* d_ws, size_t ws_size,
                              hipStream_t stream) {
  const float* x0 = (const float*)d_in[0];
  const float* x1 = (const float*)d_in[1];
  const float* h0 = (const float*)d_in[2];
  const float* h1 = (const float*)d_in[3];
  const float* W1 = (const float*)d_in[4];
  const float* b1 = (const float*)d_in[5];
  const float* W2 = (const float*)d_in[6];
  const float* b2 = (const float*)d_in[7];
  const float* Wm = (const float*)d_in[8];
  float* slot0 = (float*)d_out;                       // first output copy
  float* slot1 = slot0 + (size_t)MDIM * HDIM;         // second output copy

  if (ws_size >= FULL_NEED) {
    char* ws = (char*)d_ws;
    u16* W1t = (u16*)(ws + OFF_W1T);
    u16* W2t = (u16*)(ws + OFF_W2T);
    u16* Wmt = (u16*)(ws + OFF_WMT);
    u16* sbf = (u16*)(ws + OFF_SBF);
    u16* Z   = (u16*)(ws + OFF_Z);

    transpose_cvt<<<dim3(NDIM / 32, KGATE / 32), 256, 0, stream>>>(W1, W1t, KGATE, NDIM);
    transpose_cvt<<<dim3(NDIM / 32, KGATE / 32), 256, 0, stream>>>(W2, W2t, KGATE, NDIM);
    transpose_cvt<<<dim3(NDIM / 32, SHDIM / 32), 256, 0, stream>>>(Wm, Wmt, SHDIM, NDIM);
    build_sZ<<<MDIM, 256, 0, stream>>>(x0, x1, h0, h1, sbf, Z);

    gemm_epi<0><<<dim3(MDIM / 128, NDIM / 128), 256, 0, stream>>>(sbf, Wmt, SHDIM, nullptr, slot0, slot1);
    gemm_epi<1><<<dim3(MDIM / 128, NDIM / 128), 256, 0, stream>>>(Z, W2t, KGATE, b2, slot0, slot1);
    gemm_epi<2><<<dim3(MDIM / 128, NDIM / 128), 256, 0, stream>>>(Z, W1t, KGATE, b1, slot0, slot1);
  } else {
    fprintf(stderr, "[TensorizedRNN] fallback path: ws_size=%zu < needed=%zu\n",
            ws_size, FULL_NEED);
    slow_gemm<0><<<dim3(MDIM / 64, NDIM / 64), 256, 0, stream>>>(x0, x1, h0, h1, Wm, SHDIM, nullptr, slot0, slot1);
    slow_gemm<1><<<dim3(MDIM / 64, NDIM / 64), 256, 0, stream>>>(x0, x1, h0, h1, W2, KGATE, b2, slot0, slot1);
    slow_gemm<2><<<dim3(MDIM / 64, NDIM / 64), 256, 0, stream>>>(x0, x1, h0, h1, W1, KGATE, b1, slot0, slot1);
  }
}

// Round 2
// 2416.361 us; speedup vs baseline: 1.1428x; 1.1428x over previous
//
#include <hip/hip_runtime.h>
#include <hip/hip_bf16.h>
#include <cstdio>
#include <cstdint>

// Problem dims (fixed)
#define MDIM  4096   // batch
#define HDIM  2048   // hidden
#define SHDIM 4096   // 2H
#define KGATE 32768  // 8 * 2H
#define NDIM  2048   // output cols per gate

typedef __attribute__((ext_vector_type(8))) short short8;
typedef __attribute__((ext_vector_type(4))) float f32x4;
typedef unsigned short u16;

__device__ __forceinline__ u16 f2b(float f) {
  __hip_bfloat16 h = __float2bfloat16(f);
  return __builtin_bit_cast(u16, h);
}

// async global->LDS DMA, 16B per lane. LDS dest is wave-uniform base + lane*16
// (m104/m108) — we choose each lane's GLOBAL source to implement the swizzle.
__device__ __forceinline__ void gld_lds16(const u16* g, u16* l) {
  __builtin_amdgcn_global_load_lds((const __attribute__((address_space(1))) void*)g,
                                   (__attribute__((address_space(3))) void*)l,
                                   16, 0, 0);
}

// ---------------- ws layout (bytes) ----------------
static const size_t SZ_WT    = (size_t)NDIM * KGATE * 2;   // one gate W, bf16, [N,K]
static const size_t OFF_W1T  = 0;
static const size_t OFF_W2T  = OFF_W1T + SZ_WT;
static const size_t OFF_WMT  = OFF_W2T + SZ_WT;
static const size_t SZ_WMT   = (size_t)NDIM * SHDIM * 2;
static const size_t OFF_SBF  = OFF_WMT + SZ_WMT;
static const size_t SZ_SBF   = (size_t)MDIM * SHDIM * 2;
static const size_t OFF_Z    = OFF_SBF + SZ_SBF;
static const size_t SZ_Z     = (size_t)MDIM * KGATE * 2;
static const size_t FULL_NEED = OFF_Z + SZ_Z;              // 587202560 (560 MiB)

// ---------------- prep kernels ----------------

// src fp32 [R][C] row-major -> dst bf16 [C][R] row-major (k-major GEMM B).
// 64x64 tile per block; float4 loads, ushort4 stores.
__global__ __launch_bounds__(256) void transpose_cvt(const float* __restrict__ src,
                                                     u16* __restrict__ dst,
                                                     int R, int C) {
  __shared__ u16 t[64][65];
  const int tid = threadIdx.x;
  const int r0 = blockIdx.y << 6, c0 = blockIdx.x << 6;
  const int lr = tid >> 4;            // 0..15
  const int lc4 = (tid & 15) * 4;     // col group of 4
  #pragma unroll
  for (int rr = 0; rr < 64; rr += 16) {
    float4 v = *(const float4*)(src + (size_t)(r0 + lr + rr) * C + (c0 + lc4));
    t[lc4 + 0][lr + rr] = f2b(v.x);
    t[lc4 + 1][lr + rr] = f2b(v.y);
    t[lc4 + 2][lr + rr] = f2b(v.z);
    t[lc4 + 3][lr + rr] = f2b(v.w);
  }
  __syncthreads();
  const int rb = (tid & 15) * 4;
  #pragma unroll
  for (int cc = 0; cc < 64; cc += 16) {
    const int c = cc + (tid >> 4);
    ushort4 o = make_ushort4(t[c][rb], t[c][rb + 1], t[c][rb + 2], t[c][rb + 3]);
    *(ushort4*)(dst + (size_t)(c0 + c) * R + (r0 + rb)) = o;
  }
}

// Build s_bf16 [M][4096] and Z [M][32768], Z[l][i*4096+j] = bf16(x[l,i]*s[l,j])
__global__ __launch_bounds__(256) void build_sZ(const float* __restrict__ x0, const float* __restrict__ x1,
                                                const float* __restrict__ h0, const float* __restrict__ h1,
                                                u16* __restrict__ sbf, u16* __restrict__ Z) {
  const int l = blockIdx.x;
  float xv[8];
  #pragma unroll
  for (int i = 0; i < 4; ++i) { xv[i] = x0[l * 4 + i]; xv[4 + i] = x1[l * 4 + i]; }
  const float4* h0v = (const float4*)(h0 + (size_t)l * HDIM);
  const float4* h1v = (const float4*)(h1 + (size_t)l * HDIM);
  u16* srow = sbf + (size_t)l * SHDIM;
  u16* zrow = Z + (size_t)l * KGATE;
  for (int jj = threadIdx.x; jj < SHDIM / 4; jj += 256) {
    float4 sv = (jj < HDIM / 4) ? h0v[jj] : h1v[jj - HDIM / 4];
    ushort4 sb = make_ushort4(f2b(sv.x), f2b(sv.y), f2b(sv.z), f2b(sv.w));
    ((ushort4*)srow)[jj] = sb;
    #pragma unroll
    for (int i = 0; i < 8; ++i) {
      float xs = xv[i];
      ushort4 zb = make_ushort4(f2b(sv.x * xs), f2b(sv.y * xs), f2b(sv.z * xs), f2b(sv.w * xs));
      ((ushort4*)(zrow + (size_t)i * SHDIM))[jj] = zb;
    }
  }
}

// ---------------- main MFMA GEMM (m97 structure + swizzle + ptr-incr) ----------------
// MODE 0 (dual-gate): grid (32,16,2); z=0: B=Bt0 (W1t), raw-> out0; z=1: B=Bt1 (W2t), raw-> out1.
// MODE 1 (merge+final): grid (32,16,1); B=Bt0 (Wmt); epilogue:
//   u = sigmoid(out1[idx]+b2), st = tanh(out0[idx]+b1), o = u*st + (1-u)*acc; out0=out1=o.
template <int MODE>
__global__ __launch_bounds__(256, 4)
void gemm_k(const u16* __restrict__ A, const u16* __restrict__ Bt0, const u16* __restrict__ Bt1,
            int K, const float* __restrict__ bias1, const float* __restrict__ bias2,
            float* __restrict__ out0, float* __restrict__ out1) {
  __shared__ __attribute__((aligned(16))) u16 Atile[128 * 32];
  __shared__ __attribute__((aligned(16))) u16 Btile[128 * 32];

  const int tid  = threadIdx.x;
  const int lane = tid & 63;
  const int wave = tid >> 6;
  const int wM = wave & 1;
  const int wN = wave >> 1;
  const int mq = lane >> 4;   // k-chunk index for fragments
  const int mr = lane & 15;   // row/col within 16
  const int l4 = lane >> 2;   // row within 16-row DMA chunk
  // XOR-swizzled global k-chunk for this DMA lane: LDS(r, slot s) holds global
  // chunk s ^ (r&3); readers use slot = mq ^ (mr&3).
  const int kcs = (((lane & 3) ^ (l4 & 3))) * 8;

  const u16* Bt = Bt0;
  float* outR = out0;
  if (MODE == 0 && blockIdx.z) { Bt = Bt1; outR = out1; }

  const size_t Abase = (size_t)blockIdx.x * 128 * K;
  const size_t Bbase = (size_t)blockIdx.y * 128 * K;

  const u16* ap[2];
  const u16* bp[2];
  u16* alds[2];
  u16* blds[2];
  #pragma unroll
  for (int q = 0; q < 2; ++q) {
    const int chunk = wave * 2 + q;
    const int row = chunk * 16 + l4;
    ap[q] = A  + Abase + (size_t)row * K + kcs;
    bp[q] = Bt + Bbase + (size_t)row * K + kcs;
    alds[q] = Atile + chunk * 512;
    blds[q] = Btile + chunk * 512;
  }

  f32x4 acc[4][4];
  const f32x4 zero = {0.f, 0.f, 0.f, 0.f};
  #pragma unroll
  for (int r = 0; r < 4; ++r)
    #pragma unroll
    for (int c = 0; c < 4; ++c) acc[r][c] = zero;

  const int slot = (mq ^ (mr & 3)) * 8;
  const int nkt = K >> 5;
  for (int kt = 0; kt < nkt; ++kt) {
    #pragma unroll
    for (int q = 0; q < 2; ++q) {
      gld_lds16(ap[q], alds[q]);
      gld_lds16(bp[q], blds[q]);
    }
    __syncthreads();  // drains vmcnt(0) -> DMA visible
    short8 af[4], bfr[4];
    #pragma unroll
    for (int r = 0; r < 4; ++r)
      af[r] = *(const short8*)(Atile + (wM * 64 + r * 16 + mr) * 32 + slot);
    #pragma unroll
    for (int c = 0; c < 4; ++c)
      bfr[c] = *(const short8*)(Btile + (wN * 64 + c * 16 + mr) * 32 + slot);
    #pragma unroll
    for (int r = 0; r < 4; ++r)
      #pragma unroll
      for (int c = 0; c < 4; ++c)
        acc[r][c] = __builtin_amdgcn_mfma_f32_16x16x32_bf16(af[r], bfr[c], acc[r][c], 0, 0, 0);
    __syncthreads();  // protect tiles before next DMA
    #pragma unroll
    for (int q = 0; q < 2; ++q) { ap[q] += 32; bp[q] += 32; }
  }

  const int row0 = blockIdx.x * 128 + wM * 64;
  const int col0 = blockIdx.y * 128 + wN * 64;
  #pragma unroll
  for (int r = 0; r < 4; ++r) {
    #pragma unroll
    for (int c = 0; c < 4; ++c) {
      const int col = col0 + c * 16 + mr;
      float b1c = 0.f, b2c = 0.f;
      if constexpr (MODE == 1) { b1c = bias1[col]; b2c = bias2[col]; }
      #pragma unroll
      for (int e = 0; e < 4; ++e) {
        const int row = row0 + r * 16 + mq * 4 + e;  // C/D: col=lane&15, row=(lane>>4)*4+e
        const size_t idx = (size_t)row * NDIM + col;
        if constexpr (MODE == 0) {
          outR[idx] = acc[r][c][e];
        } else {
          const float g1 = out0[idx];
          const float g2 = out1[idx];
          const float u = 1.f / (1.f + __expf(-(g2 + b2c)));
          const float st = tanhf(g1 + b1c);
          const float o = u * st + (1.f - u) * acc[r][c][e];
          out0[idx] = o;
          out1[idx] = o;
        }
      }
    }
  }
}

// ---------------- correct-but-slow fp32 fallback (if ws too small) ----------------
template <int EPI>
__global__ __launch_bounds__(256)
void slow_gemm(const float* __restrict__ x0, const float* __restrict__ x1,
               const float* __restrict__ h0, const float* __restrict__ h1,
               const float* __restrict__ W, int KK, const float* __restrict__ bias,
               float* __restrict__ slot0, float* __restrict__ slot1) {
  __shared__ float As[64][16];
  __shared__ float Bs[16][65];
  const int tx = threadIdx.x & 15, ty = threadIdx.x >> 4;
  const int bM = blockIdx.x, bN = blockIdx.y;
  float acc[4][4] = {};
  for (int k0 = 0; k0 < KK; k0 += 16) {
    for (int t = threadIdx.x; t < 64 * 16; t += 256) {
      int r = t >> 4, kk = t & 15;
      int gk = k0 + kk;
      int row = bM * 64 + r;
      int j = (EPI == 0) ? gk : (gk & (SHDIM - 1));
      float sv = (j < HDIM) ? h0[(size_t)row * HDIM + j] : h1[(size_t)row * HDIM + j - HDIM];
      if (EPI != 0) {
        int i = gk >> 12;
        float xvv = (i < 4) ? x0[row * 4 + i] : x1[row * 4 + i - 4];
        sv *= xvv;
      }
      As[r][kk] = sv;
    }
    for (int t = threadIdx.x; t < 16 * 64; t += 256) {
      int kk = t >> 6, n = t & 63;
      Bs[kk][n] = W[(size_t)(k0 + kk) * NDIM + bN * 64 + n];
    }
    __syncthreads();
    #pragma unroll
    for (int kk = 0; kk < 16; ++kk)
      #pragma unroll
      for (int a = 0; a < 4; ++a)
        #pragma unroll
        for (int b = 0; b < 4; ++b)
          acc[a][b] = fmaf(As[ty * 4 + a][kk], Bs[kk][tx * 4 + b], acc[a][b]);
    __syncthreads();
  }
  #pragma unroll
  for (int a = 0; a < 4; ++a)
    #pragma unroll
    for (int b = 0; b < 4; ++b) {
      int row = bM * 64 + ty * 4 + a, col = bN * 64 + tx * 4 + b;
      float bcol = (EPI != 0) ? bias[col] : 0.f;
      float v = acc[a][b];
      size_t idx = (size_t)row * NDIM + col;
      if (EPI == 0) {
        slot1[idx] = v;
      } else if (EPI == 1) {
        float u = 1.f / (1.f + __expf(-(v + bcol)));
        float m = slot1[idx];
        slot1[idx] = (1.f - u) * m;
        slot0[idx] = u;
      } else {
        float st = tanhf(v + bcol);
        float o = fmaf(slot0[idx], st, slot1[idx]);
        slot0[idx] = o;
        slot1[idx] = o;
      }
    }
}

// ---------------- host ----------------
extern "C" void kernel_launch(void* const* d_in, const int* in_sizes, int n_in,
                              void* d_out, int out_size, void* d_ws, size_t ws_size,
                              hipStream_t stream) {
  const float* x0 = (const float*)d_in[0];
  const float* x1 = (const float*)d_in[1];
  const float* h0 = (const float*)d_in[2];
  const float* h1 = (const float*)d_in[3];
  const float* W1 = (const float*)d_in[4];
  const float* b1 = (const float*)d_in[5];
  const float* W2 = (const float*)d_in[6];
  const float* b2 = (const float*)d_in[7];
  const float* Wm = (const float*)d_in[8];
  float* slot0 = (float*)d_out;
  float* slot1 = slot0 + (size_t)MDIM * HDIM;

  if (ws_size >= FULL_NEED) {
    char* ws = (char*)d_ws;
    u16* W1t = (u16*)(ws + OFF_W1T);
    u16* W2t = (u16*)(ws + OFF_W2T);
    u16* Wmt = (u16*)(ws + OFF_WMT);
    u16* sbf = (u16*)(ws + OFF_SBF);
    u16* Z   = (u16*)(ws + OFF_Z);

    transpose_cvt<<<dim3(NDIM / 64, KGATE / 64), 256, 0, stream>>>(W1, W1t, KGATE, NDIM);
    transpose_cvt<<<dim3(NDIM / 64, KGATE / 64), 256, 0, stream>>>(W2, W2t, KGATE, NDIM);
    transpose_cvt<<<dim3(NDIM / 64, SHDIM / 64), 256, 0, stream>>>(Wm, Wmt, SHDIM, NDIM);
    build_sZ<<<MDIM, 256, 0, stream>>>(x0, x1, h0, h1, sbf, Z);

    // Both gate GEMMs in ONE launch (1024 blocks -> ~4 resident blocks/CU):
    // z=0: g1 = Z @ W1t^T raw -> slot0 ; z=1: g2 = Z @ W2t^T raw -> slot1
    gemm_k<0><<<dim3(MDIM / 128, NDIM / 128, 2), 256, 0, stream>>>(
        Z, W1t, W2t, KGATE, nullptr, nullptr, slot0, slot1);
    // Merge GEMM + fused final epilogue (reads g1,g2 from slots, writes o to both)
    gemm_k<1><<<dim3(MDIM / 128, NDIM / 128, 1), 256, 0, stream>>>(
        sbf, Wmt, nullptr, SHDIM, b1, b2, slot0, slot1);
  } else {
    fprintf(stderr, "[TensorizedRNN] fallback path: ws_size=%zu < needed=%zu\n",
            ws_size, FULL_NEED);
    slow_gemm<0><<<dim3(MDIM / 64, NDIM / 64), 256, 0, stream>>>(x0, x1, h0, h1, Wm, SHDIM, nullptr, slot0, slot1);
    slow_gemm<1><<<dim3(MDIM / 64, NDIM / 64), 256, 0, stream>>>(x0, x1, h0, h1, W2, KGATE, b2, slot0, slot1);
    slow_gemm<2><<<dim3(MDIM / 64, NDIM / 64), 256, 0, stream>>>(x0, x1, h0, h1, W1, KGATE, b1, slot0, slot1);
  }
}